// Round 14
// baseline (1181.284 us; speedup 1.0000x reference)
//
#include <hip/hip_runtime.h>
#include <math.h>

// Problem constants
#define Dn   1024
#define Hn   16
#define HDn  64
#define Tn   1024
#define Bn   4
#define Vn   32000
#define Ln   3
#define NT   (Bn*Tn)        // 4096 token rows

typedef __attribute__((ext_vector_type(8))) short bf16x8;
typedef __attribute__((ext_vector_type(4))) float f32x4;
typedef __attribute__((ext_vector_type(8))) unsigned short u16x8;

__device__ __forceinline__ float b2f(unsigned short u) {
  union { float f; unsigned int i; } c; c.i = ((unsigned int)u) << 16; return c.f;
}
__device__ __forceinline__ unsigned short f2b(float f) {
  union { float f; unsigned int i; } c; c.f = f;
  unsigned int r = (c.i + 0x7FFFu + ((c.i >> 16) & 1u)) >> 16;
  return (unsigned short)r;
}

#define GLOAD_LDS16(g, l) __builtin_amdgcn_global_load_lds( \
    (const __attribute__((address_space(1))) void*)(g),     \
    (__attribute__((address_space(3))) void*)(l), 16, 0, 0)

#define SBAR()  __builtin_amdgcn_s_barrier()
#define SCHED() __builtin_amdgcn_sched_barrier(0)

// XCD-aware bijective block swizzle (requires nwg % 8 == 0):
// XCD x (round-robin on linear id) gets the contiguous work range
// [x*nwg/8, (x+1)*nwg/8) -> B-panels / KV blocks become XCD-local L2 hits.
__device__ __forceinline__ int xcd_swz_lin(int lin, int nwg) {
  return (lin & 7) * (nwg >> 3) + (lin >> 3);
}

// ---------------- embedding: x = tok_emb[idx] + pos_emb[t] (fp32) ----------
__global__ __launch_bounds__(256) void embed_kernel(
    const int* __restrict__ idx, const float* __restrict__ tok,
    const float* __restrict__ pos, float* __restrict__ x) {
  int row = blockIdx.x;
  int t = row & (Tn - 1);
  int token = idx[row];
  const float4* tp = (const float4*)(tok + (size_t)token * Dn);
  const float4* pp = (const float4*)(pos + (size_t)t * Dn);
  float4* xp = (float4*)(x + (size_t)row * Dn);
  int i = threadIdx.x;
  float4 a = tp[i], b = pp[i];
  xp[i] = make_float4(a.x + b.x, a.y + b.y, a.z + b.z, a.w + b.w);
}

// ---------------- LayerNorm: fp32 in, bf16 out -----------------------------
__global__ __launch_bounds__(256) void ln_kernel(
    const float* __restrict__ x, const float* __restrict__ g,
    const float* __restrict__ b, unsigned short* __restrict__ y) {
  int row = blockIdx.x;
  const float4* xr = (const float4*)(x + (size_t)row * Dn);
  __shared__ float red[4];
  int lane = threadIdx.x & 63, w = threadIdx.x >> 6;

  float4 v = xr[threadIdx.x];
  float s = v.x + v.y + v.z + v.w;
  #pragma unroll
  for (int o = 32; o > 0; o >>= 1) s += __shfl_down(s, o, 64);
  if (lane == 0) red[w] = s;
  __syncthreads();
  float mu = (red[0] + red[1] + red[2] + red[3]) * (1.0f / Dn);
  __syncthreads();

  float dx = v.x - mu, dy = v.y - mu, dz = v.z - mu, dw = v.w - mu;
  float ss = dx*dx + dy*dy + dz*dz + dw*dw;
  #pragma unroll
  for (int o = 32; o > 0; o >>= 1) ss += __shfl_down(ss, o, 64);
  if (lane == 0) red[w] = ss;
  __syncthreads();
  float var = (red[0] + red[1] + red[2] + red[3]) * (1.0f / Dn);
  float inv = rsqrtf(var + 1e-5f);

  float4 gv = ((const float4*)g)[threadIdx.x];
  float4 bv = ((const float4*)b)[threadIdx.x];
  ushort4 o4;
  o4.x = f2b(dx*inv*gv.x + bv.x);
  o4.y = f2b(dy*inv*gv.y + bv.y);
  o4.z = f2b(dz*inv*gv.z + bv.z);
  o4.w = f2b(dw*inv*gv.w + bv.w);
  ((ushort4*)(y + (size_t)row * Dn))[threadIdx.x] = o4;
}

// ---------------- weight transpose-cast (vectorized 64x64 tiles) -----------
__global__ __launch_bounds__(256) void wcast_kernel(
    const float* __restrict__ src, unsigned short* __restrict__ dst,
    int K, int M, long long bsk, long long bsh) {
  __shared__ float t[64][65];
  const int m0 = blockIdx.x << 6, k0 = blockIdx.y << 6;
  const int tid = threadIdx.x;
  const int ml = (tid & 15) << 2;       // 0..60 step 4
  const int kl = tid >> 4;              // 0..15
  #pragma unroll
  for (int p = 0; p < 4; ++p) {
    int k = k0 + kl + p * 16;
    int m = m0 + ml;
    float4 v = *(const float4*)&src[(size_t)k * bsk + (size_t)(m >> 6) * bsh + (m & 63)];
    t[ml + 0][kl + p * 16] = v.x;
    t[ml + 1][kl + p * 16] = v.y;
    t[ml + 2][kl + p * 16] = v.z;
    t[ml + 3][kl + p * 16] = v.w;
  }
  __syncthreads();
  const int kl2 = (tid & 7) << 3;       // 0..56 step 8
  const int ml2 = tid >> 3;             // 0..31
  #pragma unroll
  for (int p = 0; p < 2; ++p) {
    int mloc = ml2 + p * 32;
    u16x8 w8;
    #pragma unroll
    for (int j = 0; j < 8; ++j) w8[j] = f2b(t[mloc][kl2 + j]);
    *(u16x8*)&dst[(size_t)(m0 + mloc) * K + k0 + kl2] = w8;
  }
}

// ---------------- fused QKV wcast (vectorized, 3 sources, one launch) ------
__global__ __launch_bounds__(256) void wcast3_kernel(
    const float* __restrict__ s0, const float* __restrict__ s1,
    const float* __restrict__ s2, unsigned short* __restrict__ dst) {
  const float* src = (blockIdx.z == 0) ? s0 : (blockIdx.z == 1) ? s1 : s2;
  unsigned short* d = dst + (size_t)blockIdx.z * 1024 * Dn;
  __shared__ float t[64][65];
  const int m0 = blockIdx.x << 6, k0 = blockIdx.y << 6;
  const int tid = threadIdx.x;
  const int ml = (tid & 15) << 2;
  const int kl = tid >> 4;
  #pragma unroll
  for (int p = 0; p < 4; ++p) {
    int k = k0 + kl + p * 16;
    int m = m0 + ml;
    float4 v = *(const float4*)&src[(size_t)k * HDn + (size_t)(m >> 6) * (Dn * HDn) + (m & 63)];
    t[ml + 0][kl + p * 16] = v.x;
    t[ml + 1][kl + p * 16] = v.y;
    t[ml + 2][kl + p * 16] = v.z;
    t[ml + 3][kl + p * 16] = v.w;
  }
  __syncthreads();
  const int kl2 = (tid & 7) << 3;
  const int ml2 = tid >> 3;
  #pragma unroll
  for (int p = 0; p < 2; ++p) {
    int mloc = ml2 + p * 32;
    u16x8 w8;
    #pragma unroll
    for (int j = 0; j < 8; ++j) w8[j] = f2b(t[mloc][kl2 + j]);
    *(u16x8*)&d[(size_t)(m0 + mloc) * Dn + k0 + kl2] = w8;
  }
}

// ---------------- bf16 MFMA GEMM (128x128, BK=32, 8 waves, 3-buf 1-bar) ----
// Used where M is small (proj, mlp2). grid = (N/128, M/128), n fast.
__global__ __launch_bounds__(512) void mm_bf16(
    const unsigned short* __restrict__ A, const unsigned short* __restrict__ BT,
    const float* __restrict__ bias, const float* __restrict__ res,
    float* __restrict__ Cf, unsigned short* __restrict__ Ch,
    int N, int K, int M, int relu) {
  __shared__ __align__(16) unsigned short As[3][128 * 32];
  __shared__ __align__(16) unsigned short Bs[3][128 * 32];
  const int tid = threadIdx.x;
  const int lane = tid & 63, w = tid >> 6, g = lane >> 4;
  const int wr = w >> 2, wc = w & 3;
  const int gx = gridDim.x;
  const int swz = xcd_swz_lin(blockIdx.y * gx + blockIdx.x, gx * gridDim.y);
  const int n0 = (swz % gx) << 7, m0 = (swz / gx) << 7;

  f32x4 acc[4][2];
  #pragma unroll
  for (int i = 0; i < 4; ++i)
    #pragma unroll
    for (int j = 0; j < 2; ++j)
      acc[i][j] = (f32x4){0.f, 0.f, 0.f, 0.f};

  const int srow = tid >> 2, su = tid & 3;
  const int sks = su ^ ((srow >> 1) & 3);
  const unsigned short* a_g = A + (size_t)(n0 + srow) * K + sks * 8;
  const unsigned short* b_g = BT + (size_t)(m0 + srow) * K + sks * 8;

  int a_off[4], b_off[2];
  #pragma unroll
  for (int f = 0; f < 4; ++f) {
    int row = wr * 64 + f * 16 + (lane & 15);
    a_off[f] = row * 64 + ((g ^ ((row >> 1) & 3)) << 4);
  }
  #pragma unroll
  for (int f = 0; f < 2; ++f) {
    int col = wc * 32 + f * 16 + (lane & 15);
    b_off[f] = col * 64 + ((g ^ ((col >> 1) & 3)) << 4);
  }

#define MM_STAGE(buf, kk) do {                                   \
    GLOAD_LDS16(a_g + (kk), As[buf] + tid * 8);                  \
    GLOAD_LDS16(b_g + (kk), Bs[buf] + tid * 8); } while (0)

#define MM_COMPUTE(buf) do {                                     \
    bf16x8 af[4], bfr[2];                                        \
    _Pragma("unroll")                                            \
    for (int f = 0; f < 4; ++f)                                  \
      af[f] = *(const bf16x8*)((const char*)As[buf] + a_off[f]); \
    _Pragma("unroll")                                            \
    for (int f = 0; f < 2; ++f)                                  \
      bfr[f] = *(const bf16x8*)((const char*)Bs[buf] + b_off[f]);\
    _Pragma("unroll")                                            \
    for (int i = 0; i < 4; ++i)                                  \
      _Pragma("unroll")                                          \
      for (int j = 0; j < 2; ++j)                                \
        acc[i][j] = __builtin_amdgcn_mfma_f32_16x16x32_bf16(af[i], bfr[j], acc[i][j], 0, 0, 0); } while (0)

  MM_STAGE(0, 0);
  MM_STAGE(1, 32);
  int bc = 0, bp = 2;
  for (int k0 = 0; k0 < K; k0 += 32) {
    if (k0 + 32 < K) asm volatile("s_waitcnt vmcnt(2)" ::: "memory");
    else             asm volatile("s_waitcnt vmcnt(0)" ::: "memory");
    SCHED(); SBAR(); SCHED();
    if (k0 + 64 < K) MM_STAGE(bp, k0 + 64);
    MM_COMPUTE(bc);
    bc = (bc == 2) ? 0 : bc + 1;
    bp = (bp == 2) ? 0 : bp + 1;
  }

  #pragma unroll
  for (int fc = 0; fc < 2; ++fc) {
    int colg = m0 + wc * 32 + fc * 16 + (lane & 15);
    float bz = bias ? bias[colg] : 0.f;
    #pragma unroll
    for (int fr = 0; fr < 4; ++fr) {
      #pragma unroll
      for (int i = 0; i < 4; ++i) {
        int rowg = n0 + wr * 64 + fr * 16 + (g << 2) + i;
        float v = acc[fr][fc][i] + bz;
        if (res) v += res[(size_t)rowg * M + colg];
        if (relu) v = fmaxf(v, 0.f);
        if (Cf) Cf[(size_t)rowg * M + colg] = v;
        else    Ch[(size_t)rowg * M + colg] = f2b(v);
      }
    }
  }
#undef MM_STAGE
#undef MM_COMPUTE
}

// ---------------- bf16 MFMA GEMM (128x256, BK=32, 8 waves, 3-buf 1-bar) ----
// 512 threads, waves 2(M)x4(N), per-wave 64x64. grid = (N/128, M/256), n fast.
// OMODE 0: row-major out + bias/res/relu
// OMODE 3: fused QKV (M=3072)
// OMODE 4: LM head: fp32 out (nontemporal) + bias + per-row sum(exp) atomicAdd
template<int OMODE>
__global__ __launch_bounds__(512) void mm512_bf16(
    const unsigned short* __restrict__ A, const unsigned short* __restrict__ BT,
    const float* __restrict__ bias, const float* __restrict__ res,
    float* __restrict__ Cf, unsigned short* __restrict__ Ch,
    float* __restrict__ rowsum, int N, int K, int M, int relu) {
  __shared__ __align__(16) unsigned short As[3][128 * 32];
  __shared__ __align__(16) unsigned short Bs[3][256 * 32];
  __shared__ float rsum2[OMODE == 4 ? 128 * 4 : 4];
  const int tid = threadIdx.x;
  const int lane = tid & 63, w = tid >> 6, g = lane >> 4;
  const int wr = w >> 2, wc = w & 3;
  const int gx = gridDim.x;
  const int swz = xcd_swz_lin(blockIdx.y * gx + blockIdx.x, gx * gridDim.y);
  const int n0 = (swz % gx) << 7, m0 = (swz / gx) << 8;

  f32x4 acc[4][4];
  #pragma unroll
  for (int i = 0; i < 4; ++i)
    #pragma unroll
    for (int j = 0; j < 4; ++j)
      acc[i][j] = (f32x4){0.f, 0.f, 0.f, 0.f};

  const int arow = tid >> 2, au = tid & 3;
  const int aks = au ^ ((arow >> 1) & 3);
  const unsigned short* a_g = A + (size_t)(n0 + arow) * K + aks * 8;
  const int brow1 = (tid + 512) >> 2;
  const int bks0 = au ^ ((arow >> 1) & 3);
  const int bks1 = au ^ ((brow1 >> 1) & 3);
  const unsigned short* b_g0 = BT + (size_t)(m0 + arow) * K + bks0 * 8;
  const unsigned short* b_g1 = BT + (size_t)(m0 + brow1) * K + bks1 * 8;

  int a_off[4], b_off[4];
  #pragma unroll
  for (int f = 0; f < 4; ++f) {
    int row = wr * 64 + f * 16 + (lane & 15);
    a_off[f] = row * 64 + ((g ^ ((row >> 1) & 3)) << 4);
    int col = wc * 64 + f * 16 + (lane & 15);
    b_off[f] = col * 64 + ((g ^ ((col >> 1) & 3)) << 4);
  }

#define MM5_STAGE(buf, kk) do {                                  \
    GLOAD_LDS16(a_g + (kk), As[buf] + tid * 8);                  \
    GLOAD_LDS16(b_g0 + (kk), Bs[buf] + tid * 8);                 \
    GLOAD_LDS16(b_g1 + (kk), Bs[buf] + (tid + 512) * 8); } while (0)

#define MM5_COMPUTE(buf) do {                                    \
    bf16x8 af[4], bfr[4];                                        \
    _Pragma("unroll")                                            \
    for (int f = 0; f < 4; ++f) {                                \
      af[f]  = *(const bf16x8*)((const char*)As[buf] + a_off[f]);\
      bfr[f] = *(const bf16x8*)((const char*)Bs[buf] + b_off[f]);\
    }                                                            \
    _Pragma("unroll")                                            \
    for (int i = 0; i < 4; ++i)                                  \
      _Pragma("unroll")                                          \
      for (int j = 0; j < 4; ++j)                                \
        acc[i][j] = __builtin_amdgcn_mfma_f32_16x16x32_bf16(af[i], bfr[j], acc[i][j], 0, 0, 0); } while (0)

  MM5_STAGE(0, 0);
  MM5_STAGE(1, 32);
  int bc = 0, bp = 2;
  for (int k0 = 0; k0 < K; k0 += 32) {
    if (k0 + 32 < K) asm volatile("s_waitcnt vmcnt(3)" ::: "memory");
    else             asm volatile("s_waitcnt vmcnt(0)" ::: "memory");
    SCHED(); SBAR(); SCHED();
    if (k0 + 64 < K) MM5_STAGE(bp, k0 + 64);  // safe: readers finished before barrier
    MM5_COMPUTE(bc);
    bc = (bc == 2) ? 0 : bc + 1;
    bp = (bp == 2) ? 0 : bp + 1;
  }

  if (OMODE == 0) {
    #pragma unroll
    for (int fc = 0; fc < 4; ++fc) {
      int colg = m0 + wc * 64 + fc * 16 + (lane & 15);
      float bz = bias ? bias[colg] : 0.f;
      #pragma unroll
      for (int fr = 0; fr < 4; ++fr) {
        #pragma unroll
        for (int i = 0; i < 4; ++i) {
          int rowg = n0 + wr * 64 + fr * 16 + (g << 2) + i;
          float v = acc[fr][fc][i] + bz;
          if (res) v += res[(size_t)rowg * M + colg];
          if (relu) v = fmaxf(v, 0.f);
          if (Cf) Cf[(size_t)rowg * M + colg] = v;
          else    Ch[(size_t)rowg * M + colg] = f2b(v);
        }
      }
    }
  } else if (OMODE == 3) {
    unsigned short* kb  = Ch + (size_t)NT * Dn;
    unsigned short* vtb = Ch + 2 * (size_t)NT * Dn;
    #pragma unroll
    for (int fc = 0; fc < 4; ++fc) {
      int colg = m0 + wc * 64 + fc * 16 + (lane & 15);
      int sel = colg >> 10, hh = (colg >> 6) & 15, e = colg & 63;
      #pragma unroll
      for (int fr = 0; fr < 4; ++fr) {
        int rowg0 = n0 + wr * 64 + fr * 16 + (g << 2);
        int b = rowg0 >> 10, t0 = rowg0 & 1023;
        if (sel == 2) {
          ushort4 pk;
          pk.x = f2b(acc[fr][fc][0]); pk.y = f2b(acc[fr][fc][1]);
          pk.z = f2b(acc[fr][fc][2]); pk.w = f2b(acc[fr][fc][3]);
          *(ushort4*)&vtb[(((size_t)(b * 16 + hh) * 64) + e) * 1024 + t0] = pk;
        } else {
          unsigned short* dst = (sel == 0) ? Ch : kb;
          #pragma unroll
          for (int i = 0; i < 4; ++i)
            dst[(((size_t)(b * 16 + hh) * 1024) + t0 + i) * 64 + e] = f2b(acc[fr][fc][i]);
        }
      }
    }
  } else {
    // OMODE 4: LM head.
    #pragma unroll
    for (int fr = 0; fr < 4; ++fr) {
      #pragma unroll
      for (int i = 0; i < 4; ++i) {
        int rloc = wr * 64 + fr * 16 + (g << 2) + i;
        int rowg = n0 + rloc;
        float es = 0.f;
        #pragma unroll
        for (int fc = 0; fc < 4; ++fc) {
          int colg = m0 + wc * 64 + fc * 16 + (lane & 15);
          float v = acc[fr][fc][i] + bias[colg];
          __builtin_nontemporal_store(v, &Cf[(size_t)rowg * M + colg]);
          es += __expf(v);
        }
        es += __shfl_xor(es, 1); es += __shfl_xor(es, 2);
        es += __shfl_xor(es, 4); es += __shfl_xor(es, 8);
        if ((lane & 15) == 0) rsum2[rloc * 4 + wc] = es;
      }
    }
    __syncthreads();
    if (tid < 128)
      atomicAdd(&rowsum[n0 + tid],
                rsum2[tid * 4 + 0] + rsum2[tid * 4 + 1] +
                rsum2[tid * 4 + 2] + rsum2[tid * 4 + 3]);
  }
#undef MM5_STAGE
#undef MM5_COMPUTE
}

// ---------------- MFMA flash attention (paired q-tiles, dbuf KV + vmcnt) ---
// q,k: [B][H][T][64] bf16; vt: [B][H][64][T] bf16; out ob: [NT][D] bf16
// Block handles q-tiles {pr, 15-pr} sequentially: uniform 17 KV-steps/block.
// XCD swizzle groups the 8 pr-blocks of a (b,h) onto one XCD (KV L2-local).
__global__ __launch_bounds__(256) void fattn_kernel(
    const unsigned short* __restrict__ qg, const unsigned short* __restrict__ kg,
    const unsigned short* __restrict__ vtg, unsigned short* __restrict__ ob) {
  const int bid = xcd_swz_lin(blockIdx.x, Bn * Hn * 8);   // 512 blocks
  const int pr = bid & 7, bh = bid >> 3;
  const int b = bh >> 4, h = bh & 15;
  const int tid = threadIdx.x, lane = tid & 63, w = tid >> 6, g = lane >> 4;

  __shared__ __align__(16) unsigned short Ks[2][64 * 64];
  __shared__ __align__(16) unsigned short Vs[2][64 * 64];
  __shared__ __align__(16) unsigned short Pb[4][16 * 64];

  const unsigned short* kbase = kg + (size_t)bh * Tn * HDn;
  const unsigned short* vbase = vtg + (size_t)bh * HDn * Tn;
  const float scale = 0.03125f;                 // D^-0.5 (reference scales by n_embd)
  unsigned short* pb = &Pb[w][0];

#define FA_STAGE(buf, s0_) do {                                              \
    _Pragma("unroll")                                                        \
    for (int r = 0; r < 2; ++r) {                                            \
      int c = tid + 256 * r;                                                 \
      int srow = c >> 3, u = c & 7;                                          \
      GLOAD_LDS16(kbase + (size_t)((s0_) + srow) * HDn + ((u ^ (srow & 7)) * 8), Ks[buf] + c * 8); \
    }                                                                        \
    _Pragma("unroll")                                                        \
    for (int r = 0; r < 2; ++r) {                                            \
      int c = tid + 256 * r;                                                 \
      int d = c >> 3, u = c & 7;                                             \
      GLOAD_LDS16(vbase + (size_t)d * Tn + (s0_) + ((u ^ (d & 7)) * 8), Vs[buf] + c * 8); \
    } } while (0)

  #pragma unroll 1
  for (int half = 0; half < 2; ++half) {
    const int qt = half ? (15 - pr) : pr;
    const int qrow = qt * 64 + w * 16 + (lane & 15);
    const unsigned short* qptr = qg + ((size_t)bh * Tn + qrow) * HDn;
    bf16x8 qf0 = *(const bf16x8*)(qptr + g * 8);
    bf16x8 qf1 = *(const bf16x8*)(qptr + 32 + g * 8);

    f32x4 accO[4];
    #pragma unroll
    for (int dt = 0; dt < 4; ++dt) accO[dt] = (f32x4){0.f, 0.f, 0.f, 0.f};
    float mrun[4] = {-1e30f, -1e30f, -1e30f, -1e30f};
    float lrun[4] = {0.f, 0.f, 0.f, 0.f};
    const int qout0 = qt * 64 + w * 16 + 4 * g;
    const int nsteps = qt + 1;

    FA_STAGE(0, 0);
    int cur = 0;

    for (int st = 0; st < nsteps; ++st) {
      const int s0 = st * 64;
      if (st + 1 < nsteps) {
        FA_STAGE(cur ^ 1, s0 + 64);
        asm volatile("s_waitcnt vmcnt(4)" ::: "memory");
      } else {
        asm volatile("s_waitcnt vmcnt(0)" ::: "memory");
      }
      SCHED(); SBAR(); SCHED();

      float p[4][4];
      #pragma unroll
      for (int sub = 0; sub < 4; ++sub) {
        int srow = sub * 16 + (lane & 15);
        const char* kr = (const char*)Ks[cur] + srow * 128;
        bf16x8 kf0 = *(const bf16x8*)(kr + ((g ^ (srow & 7)) * 16));
        bf16x8 kf1 = *(const bf16x8*)(kr + (((4 + g) ^ (srow & 7)) * 16));
        f32x4 s4 = (f32x4){0.f, 0.f, 0.f, 0.f};
        s4 = __builtin_amdgcn_mfma_f32_16x16x32_bf16(qf0, kf0, s4, 0, 0, 0);
        s4 = __builtin_amdgcn_mfma_f32_16x16x32_bf16(qf1, kf1, s4, 0, 0, 0);
        int sg = s0 + srow;
        #pragma unroll
        for (int i = 0; i < 4; ++i)
          p[sub][i] = (sg > qout0 + i) ? -1e30f : s4[i] * scale;
      }

      #pragma unroll
      for (int i = 0; i < 4; ++i) {
        float v = fmaxf(fmaxf(p[0][i], p[1][i]), fmaxf(p[2][i], p[3][i]));
        v = fmaxf(v, __shfl_xor(v, 1)); v = fmaxf(v, __shfl_xor(v, 2));
        v = fmaxf(v, __shfl_xor(v, 4)); v = fmaxf(v, __shfl_xor(v, 8));
        float nm = fmaxf(mrun[i], v);
        float fac = __expf(mrun[i] - nm);
        mrun[i] = nm;
        #pragma unroll
        for (int dt = 0; dt < 4; ++dt) accO[dt][i] *= fac;
        float sum = 0.f;
        #pragma unroll
        for (int sub = 0; sub < 4; ++sub) {
          float e = __expf(p[sub][i] - nm);
          p[sub][i] = e;
          sum += e;
        }
        sum += __shfl_xor(sum, 1); sum += __shfl_xor(sum, 2);
        sum += __shfl_xor(sum, 4); sum += __shfl_xor(sum, 8);
        lrun[i] = lrun[i] * fac + sum;
      }

      #pragma unroll
      for (int sub = 0; sub < 4; ++sub) {
        int s = sub * 16 + (lane & 15);
        #pragma unroll
        for (int i = 0; i < 4; ++i) {
          int q = 4 * g + i;
          pb[q * 64 + (((s >> 3) ^ (q & 7)) * 8) + (s & 7)] = f2b(p[sub][i]);
        }
      }

      #pragma unroll
      for (int sc = 0; sc < 2; ++sc) {
        int qq = lane & 15;
        bf16x8 pa = *(const bf16x8*)((const char*)pb + qq * 128 + (((sc * 4 + g) ^ (qq & 7)) * 16));
        #pragma unroll
        for (int dt = 0; dt < 4; ++dt) {
          int d = dt * 16 + (lane & 15);
          bf16x8 vf = *(const bf16x8*)((const char*)Vs[cur] + d * 128 + (((sc * 4 + g) ^ (d & 7)) * 16));
          accO[dt] = __builtin_amdgcn_mfma_f32_16x16x32_bf16(pa, vf, accO[dt], 0, 0, 0);
        }
      }

      SCHED(); SBAR(); SCHED();
      cur ^= 1;
    }

    float rinv[4];
    #pragma unroll
    for (int i = 0; i < 4; ++i) rinv[i] = 1.0f / lrun[i];
    #pragma unroll
    for (int dt = 0; dt < 4; ++dt) {
      int dcol = h * 64 + dt * 16 + (lane & 15);
      #pragma unroll
      for (int i = 0; i < 4; ++i) {
        int t = qout0 + i;
        ob[((size_t)(b * Tn + t)) * Dn + dcol] = f2b(accO[dt][i] * rinv[i]);
      }
    }
  }
#undef FA_STAGE
}

// ---------------- final loss: nll from gathered target logit + rowsum ------
__global__ __launch_bounds__(256) void loss_kernel(
    const float* __restrict__ logits, const float* __restrict__ rowsum,
    const int* __restrict__ target, float* __restrict__ out_loss) {
  __shared__ float red[4];
  int lane = threadIdx.x & 63, w = threadIdx.x >> 6;
  float s = 0.f;
  for (int row = threadIdx.x; row < NT; row += 256) {
    float lt = logits[(size_t)row * Vn + target[row]];
    s += logf(rowsum[row]) - lt;          // -(lt - log(sum))
  }
  #pragma unroll
  for (int off = 32; off > 0; off >>= 1) s += __shfl_down(s, off, 64);
  if (lane == 0) red[w] = s;
  __syncthreads();
  if (threadIdx.x == 0)
    *out_loss = (red[0] + red[1] + red[2] + red[3]) * (1.0f / NT);
}

// ---------------------------------------------------------------------------
static inline void launch_wcast(const float* src, unsigned short* dst, int K, int M,
                                long long bsk, long long bsh, hipStream_t s) {
  dim3 g(M >> 6, K >> 6);
  wcast_kernel<<<g, 256, 0, s>>>(src, dst, K, M, bsk, bsh);
}

static inline void launch_mm(const unsigned short* A, const unsigned short* BT,
                             const float* bias, const float* res,
                             float* Cf, unsigned short* Ch,
                             int N, int K, int M, int relu, hipStream_t s) {
  dim3 g(N >> 7, M >> 7);          // n fast, m slow: B-panel temporal locality
  mm_bf16<<<g, 512, 0, s>>>(A, BT, bias, res, Cf, Ch, N, K, M, relu);
}

template<int OMODE>
static inline void launch_mm512(const unsigned short* A, const unsigned short* BT,
                                const float* bias, const float* res,
                                float* Cf, unsigned short* Ch, float* rowsum,
                                int N, int K, int M, int relu, hipStream_t s) {
  dim3 g(N >> 7, M >> 8);          // n fast, m slow
  mm512_bf16<OMODE><<<g, 512, 0, s>>>(A, BT, bias, res, Cf, Ch, rowsum, N, K, M, relu);
}

extern "C" void kernel_launch(void* const* d_in, const int* in_sizes, int n_in,
                              void* d_out, int out_size, void* d_ws, size_t ws_size,
                              hipStream_t stream) {
  const int*   idx    = (const int*)d_in[0];
  const int*   target = (const int*)d_in[1];
  const float* tok    = (const float*)d_in[2];
  const float* pos    = (const float*)d_in[3];
  const float* wq     = (const float*)d_in[4];
  const float* wk     = (const float*)d_in[5];
  const float* wv     = (const float*)d_in[6];
  const float* wproj  = (const float*)d_in[7];
  const float* bproj  = (const float*)d_in[8];
  const float* ln1g   = (const float*)d_in[9];
  const float* ln1b   = (const float*)d_in[10];
  const float* ln2g   = (const float*)d_in[11];
  const float* ln2b   = (const float*)d_in[12];
  const float* w1     = (const float*)d_in[13];
  const float* b1     = (const float*)d_in[14];
  const float* w2     = (const float*)d_in[15];
  const float* b2     = (const float*)d_in[16];
  const float* lnfg   = (const float*)d_in[17];
  const float* lnfb   = (const float*)d_in[18];
  const float* wlm    = (const float*)d_in[19];
  const float* blm    = (const float*)d_in[20];

  float* out = (float*)d_out;          // logits [4096,32000] + loss scalar

  char* p = (char*)d_ws;
  float* x  = (float*)p;                 p += (size_t)NT * Dn * 4;
  unsigned short* xn = (unsigned short*)p; p += (size_t)NT * Dn * 2;
  unsigned short* reg = (unsigned short*)p; p += (size_t)NT * 4 * Dn * 2;
  unsigned short* wT = (unsigned short*)p; p += (size_t)Vn * Dn * 2;
  float* rowsum = (float*)p;

  unsigned short* qb  = reg;                         // [B][H][T][64]
  unsigned short* kb  = reg + (size_t)NT * Dn;       // [B][H][T][64]
  unsigned short* vtb = reg + 2 * (size_t)NT * Dn;   // [B][H][64][T]
  unsigned short* ob  = reg + 3 * (size_t)NT * Dn;   // [NT][D]
  unsigned short* hb  = reg;                         // MLP hidden, disjoint in time

  embed_kernel<<<NT, 256, 0, stream>>>(idx, tok, pos, x);

  for (int l = 0; l < Ln; ++l) {
    const float* wq_l = wq + (size_t)l * Hn * Dn * HDn;
    const float* wk_l = wk + (size_t)l * Hn * Dn * HDn;
    const float* wv_l = wv + (size_t)l * Hn * Dn * HDn;

    ln_kernel<<<NT, 256, 0, stream>>>(x, ln1g + l * Dn, ln1b + l * Dn, xn);

    // fused QKV: wT rows [0,1024)=q, [1024,2048)=k, [2048,3072)=v, one launch
    {
      dim3 g3(16, 16, 3);
      wcast3_kernel<<<g3, 256, 0, stream>>>(wq_l, wk_l, wv_l, wT);
    }
    launch_mm512<3>(xn, wT, nullptr, nullptr, nullptr, qb, nullptr, NT, Dn, 3072, 0, stream);

    fattn_kernel<<<Bn * Hn * 8, 256, 0, stream>>>(qb, kb, vtb, ob);

    launch_wcast(wproj + (size_t)l * Dn * Dn, wT, Dn, Dn, Dn, 64, stream);
    launch_mm(ob, wT, bproj + l * Dn, x, x, nullptr, NT, Dn, Dn, 0, stream);

    ln_kernel<<<NT, 256, 0, stream>>>(x, ln2g + l * Dn, ln2b + l * Dn, xn);

    launch_wcast(w1 + (size_t)l * Dn * 4 * Dn, wT, Dn, 4 * Dn, 4 * Dn, 64, stream);
    launch_mm512<0>(xn, wT, b1 + l * 4 * Dn, nullptr, nullptr, hb, nullptr, NT, Dn, 4 * Dn, 1, stream);
    launch_wcast(w2 + (size_t)l * 4 * Dn * Dn, wT, 4 * Dn, Dn, Dn, 64, stream);
    launch_mm(hb, wT, b2 + l * Dn, x, x, nullptr, NT, 4 * Dn, Dn, 0, stream);
  }

  ln_kernel<<<NT, 256, 0, stream>>>(x, lnfg, lnfb, xn);

  // logits + fused per-row exp-sums
  hipMemsetAsync(rowsum, 0, NT * sizeof(float), stream);
  launch_wcast(wlm, wT, Dn, Vn, Vn, 64, stream);
  launch_mm512<4>(xn, wT, blm, nullptr, out, nullptr, rowsum, NT, Dn, Vn, 0, stream);

  loss_kernel<<<1, 256, 0, stream>>>(out, rowsum, target, out + (size_t)NT * Vn);
}

// Round 15
// 1157.804 us; speedup vs baseline: 1.0203x; 1.0203x over previous
//
#include <hip/hip_runtime.h>
#include <math.h>

// Problem constants
#define Dn   1024
#define Hn   16
#define HDn  64
#define Tn   1024
#define Bn   4
#define Vn   32000
#define Ln   3
#define NT   (Bn*Tn)        // 4096 token rows

typedef __attribute__((ext_vector_type(8))) short bf16x8;
typedef __attribute__((ext_vector_type(4))) float f32x4;
typedef __attribute__((ext_vector_type(8))) unsigned short u16x8;

__device__ __forceinline__ float b2f(unsigned short u) {
  union { float f; unsigned int i; } c; c.i = ((unsigned int)u) << 16; return c.f;
}
__device__ __forceinline__ unsigned short f2b(float f) {
  union { float f; unsigned int i; } c; c.f = f;
  unsigned int r = (c.i + 0x7FFFu + ((c.i >> 16) & 1u)) >> 16;
  return (unsigned short)r;
}

#define GLOAD_LDS16(g, l) __builtin_amdgcn_global_load_lds( \
    (const __attribute__((address_space(1))) void*)(g),     \
    (__attribute__((address_space(3))) void*)(l), 16, 0, 0)

#define SBAR()  __builtin_amdgcn_s_barrier()
#define SCHED() __builtin_amdgcn_sched_barrier(0)

// ---------------- embedding: x = tok_emb[idx] + pos_emb[t] (fp32) ----------
__global__ __launch_bounds__(256) void embed_kernel(
    const int* __restrict__ idx, const float* __restrict__ tok,
    const float* __restrict__ pos, float* __restrict__ x) {
  int row = blockIdx.x;
  int t = row & (Tn - 1);
  int token = idx[row];
  const float4* tp = (const float4*)(tok + (size_t)token * Dn);
  const float4* pp = (const float4*)(pos + (size_t)t * Dn);
  float4* xp = (float4*)(x + (size_t)row * Dn);
  int i = threadIdx.x;
  float4 a = tp[i], b = pp[i];
  xp[i] = make_float4(a.x + b.x, a.y + b.y, a.z + b.z, a.w + b.w);
}

// ---------------- LayerNorm: fp32 in, bf16 out -----------------------------
__global__ __launch_bounds__(256) void ln_kernel(
    const float* __restrict__ x, const float* __restrict__ g,
    const float* __restrict__ b, unsigned short* __restrict__ y) {
  int row = blockIdx.x;
  const float4* xr = (const float4*)(x + (size_t)row * Dn);
  __shared__ float red[4];
  int lane = threadIdx.x & 63, w = threadIdx.x >> 6;

  float4 v = xr[threadIdx.x];
  float s = v.x + v.y + v.z + v.w;
  #pragma unroll
  for (int o = 32; o > 0; o >>= 1) s += __shfl_down(s, o, 64);
  if (lane == 0) red[w] = s;
  __syncthreads();
  float mu = (red[0] + red[1] + red[2] + red[3]) * (1.0f / Dn);
  __syncthreads();

  float dx = v.x - mu, dy = v.y - mu, dz = v.z - mu, dw = v.w - mu;
  float ss = dx*dx + dy*dy + dz*dz + dw*dw;
  #pragma unroll
  for (int o = 32; o > 0; o >>= 1) ss += __shfl_down(ss, o, 64);
  if (lane == 0) red[w] = ss;
  __syncthreads();
  float var = (red[0] + red[1] + red[2] + red[3]) * (1.0f / Dn);
  float inv = rsqrtf(var + 1e-5f);

  float4 gv = ((const float4*)g)[threadIdx.x];
  float4 bv = ((const float4*)b)[threadIdx.x];
  ushort4 o4;
  o4.x = f2b(dx*inv*gv.x + bv.x);
  o4.y = f2b(dy*inv*gv.y + bv.y);
  o4.z = f2b(dz*inv*gv.z + bv.z);
  o4.w = f2b(dw*inv*gv.w + bv.w);
  ((ushort4*)(y + (size_t)row * Dn))[threadIdx.x] = o4;
}

// ---------------- weight transpose-cast (vectorized 64x64 tiles) -----------
__global__ __launch_bounds__(256) void wcast_kernel(
    const float* __restrict__ src, unsigned short* __restrict__ dst,
    int K, int M, long long bsk, long long bsh) {
  __shared__ float t[64][65];
  const int m0 = blockIdx.x << 6, k0 = blockIdx.y << 6;
  const int tid = threadIdx.x;
  const int ml = (tid & 15) << 2;       // 0..60 step 4
  const int kl = tid >> 4;              // 0..15
  #pragma unroll
  for (int p = 0; p < 4; ++p) {
    int k = k0 + kl + p * 16;
    int m = m0 + ml;
    float4 v = *(const float4*)&src[(size_t)k * bsk + (size_t)(m >> 6) * bsh + (m & 63)];
    t[ml + 0][kl + p * 16] = v.x;
    t[ml + 1][kl + p * 16] = v.y;
    t[ml + 2][kl + p * 16] = v.z;
    t[ml + 3][kl + p * 16] = v.w;
  }
  __syncthreads();
  const int kl2 = (tid & 7) << 3;       // 0..56 step 8
  const int ml2 = tid >> 3;             // 0..31
  #pragma unroll
  for (int p = 0; p < 2; ++p) {
    int mloc = ml2 + p * 32;
    u16x8 w8;
    #pragma unroll
    for (int j = 0; j < 8; ++j) w8[j] = f2b(t[mloc][kl2 + j]);
    *(u16x8*)&dst[(size_t)(m0 + mloc) * K + k0 + kl2] = w8;
  }
}

// ---------------- fused QKV wcast (vectorized, 3 sources, one launch) ------
__global__ __launch_bounds__(256) void wcast3_kernel(
    const float* __restrict__ s0, const float* __restrict__ s1,
    const float* __restrict__ s2, unsigned short* __restrict__ dst) {
  const float* src = (blockIdx.z == 0) ? s0 : (blockIdx.z == 1) ? s1 : s2;
  unsigned short* d = dst + (size_t)blockIdx.z * 1024 * Dn;
  __shared__ float t[64][65];
  const int m0 = blockIdx.x << 6, k0 = blockIdx.y << 6;
  const int tid = threadIdx.x;
  const int ml = (tid & 15) << 2;
  const int kl = tid >> 4;
  #pragma unroll
  for (int p = 0; p < 4; ++p) {
    int k = k0 + kl + p * 16;
    int m = m0 + ml;
    float4 v = *(const float4*)&src[(size_t)k * HDn + (size_t)(m >> 6) * (Dn * HDn) + (m & 63)];
    t[ml + 0][kl + p * 16] = v.x;
    t[ml + 1][kl + p * 16] = v.y;
    t[ml + 2][kl + p * 16] = v.z;
    t[ml + 3][kl + p * 16] = v.w;
  }
  __syncthreads();
  const int kl2 = (tid & 7) << 3;
  const int ml2 = tid >> 3;
  #pragma unroll
  for (int p = 0; p < 2; ++p) {
    int mloc = ml2 + p * 32;
    u16x8 w8;
    #pragma unroll
    for (int j = 0; j < 8; ++j) w8[j] = f2b(t[mloc][kl2 + j]);
    *(u16x8*)&d[(size_t)(m0 + mloc) * Dn + k0 + kl2] = w8;
  }
}

// ---------------- bf16 MFMA GEMM (128x128, BK=32, 8 waves, 3-buf 1-bar) ----
// Used where M is small (proj, mlp2). grid = (N/128, M/128), n fast.
__global__ __launch_bounds__(512) void mm_bf16(
    const unsigned short* __restrict__ A, const unsigned short* __restrict__ BT,
    const float* __restrict__ bias, const float* __restrict__ res,
    float* __restrict__ Cf, unsigned short* __restrict__ Ch,
    int N, int K, int M, int relu) {
  __shared__ __align__(16) unsigned short As[3][128 * 32];
  __shared__ __align__(16) unsigned short Bs[3][128 * 32];
  const int tid = threadIdx.x;
  const int lane = tid & 63, w = tid >> 6, g = lane >> 4;
  const int wr = w >> 2, wc = w & 3;
  const int n0 = blockIdx.x << 7, m0 = blockIdx.y << 7;

  f32x4 acc[4][2];
  #pragma unroll
  for (int i = 0; i < 4; ++i)
    #pragma unroll
    for (int j = 0; j < 2; ++j)
      acc[i][j] = (f32x4){0.f, 0.f, 0.f, 0.f};

  const int srow = tid >> 2, su = tid & 3;
  const int sks = su ^ ((srow >> 1) & 3);
  const unsigned short* a_g = A + (size_t)(n0 + srow) * K + sks * 8;
  const unsigned short* b_g = BT + (size_t)(m0 + srow) * K + sks * 8;

  int a_off[4], b_off[2];
  #pragma unroll
  for (int f = 0; f < 4; ++f) {
    int row = wr * 64 + f * 16 + (lane & 15);
    a_off[f] = row * 64 + ((g ^ ((row >> 1) & 3)) << 4);
  }
  #pragma unroll
  for (int f = 0; f < 2; ++f) {
    int col = wc * 32 + f * 16 + (lane & 15);
    b_off[f] = col * 64 + ((g ^ ((col >> 1) & 3)) << 4);
  }

#define MM_STAGE(buf, kk) do {                                   \
    GLOAD_LDS16(a_g + (kk), As[buf] + tid * 8);                  \
    GLOAD_LDS16(b_g + (kk), Bs[buf] + tid * 8); } while (0)

#define MM_COMPUTE(buf) do {                                     \
    bf16x8 af[4], bfr[2];                                        \
    _Pragma("unroll")                                            \
    for (int f = 0; f < 4; ++f)                                  \
      af[f] = *(const bf16x8*)((const char*)As[buf] + a_off[f]); \
    _Pragma("unroll")                                            \
    for (int f = 0; f < 2; ++f)                                  \
      bfr[f] = *(const bf16x8*)((const char*)Bs[buf] + b_off[f]);\
    _Pragma("unroll")                                            \
    for (int i = 0; i < 4; ++i)                                  \
      _Pragma("unroll")                                          \
      for (int j = 0; j < 2; ++j)                                \
        acc[i][j] = __builtin_amdgcn_mfma_f32_16x16x32_bf16(af[i], bfr[j], acc[i][j], 0, 0, 0); } while (0)

  MM_STAGE(0, 0);
  MM_STAGE(1, 32);
  int bc = 0, bp = 2;
  for (int k0 = 0; k0 < K; k0 += 32) {
    if (k0 + 32 < K) asm volatile("s_waitcnt vmcnt(2)" ::: "memory");
    else             asm volatile("s_waitcnt vmcnt(0)" ::: "memory");
    SCHED(); SBAR(); SCHED();
    if (k0 + 64 < K) MM_STAGE(bp, k0 + 64);
    MM_COMPUTE(bc);
    bc = (bc == 2) ? 0 : bc + 1;
    bp = (bp == 2) ? 0 : bp + 1;
  }

  #pragma unroll
  for (int fc = 0; fc < 2; ++fc) {
    int colg = m0 + wc * 32 + fc * 16 + (lane & 15);
    float bz = bias ? bias[colg] : 0.f;
    #pragma unroll
    for (int fr = 0; fr < 4; ++fr) {
      #pragma unroll
      for (int i = 0; i < 4; ++i) {
        int rowg = n0 + wr * 64 + fr * 16 + (g << 2) + i;
        float v = acc[fr][fc][i] + bz;
        if (res) v += res[(size_t)rowg * M + colg];
        if (relu) v = fmaxf(v, 0.f);
        if (Cf) Cf[(size_t)rowg * M + colg] = v;
        else    Ch[(size_t)rowg * M + colg] = f2b(v);
      }
    }
  }
#undef MM_STAGE
#undef MM_COMPUTE
}

// ---------------- bf16 MFMA GEMM (128x256, BK=32, 8 waves, 3-buf 1-bar) ----
// 512 threads, waves 2(M)x4(N), per-wave 64x64. grid = (N/128, M/256), n fast.
// OMODE 0: row-major out + bias/res/relu
// OMODE 3: fused QKV (M=3072)
// OMODE 4: LM head: fp32 out (nontemporal) + bias + per-row sum(exp) atomicAdd
template<int OMODE>
__global__ __launch_bounds__(512) void mm512_bf16(
    const unsigned short* __restrict__ A, const unsigned short* __restrict__ BT,
    const float* __restrict__ bias, const float* __restrict__ res,
    float* __restrict__ Cf, unsigned short* __restrict__ Ch,
    float* __restrict__ rowsum, int N, int K, int M, int relu) {
  __shared__ __align__(16) unsigned short As[3][128 * 32];
  __shared__ __align__(16) unsigned short Bs[3][256 * 32];
  __shared__ float rsum2[OMODE == 4 ? 128 * 4 : 4];
  const int tid = threadIdx.x;
  const int lane = tid & 63, w = tid >> 6, g = lane >> 4;
  const int wr = w >> 2, wc = w & 3;
  const int n0 = blockIdx.x << 7, m0 = blockIdx.y << 8;

  f32x4 acc[4][4];
  #pragma unroll
  for (int i = 0; i < 4; ++i)
    #pragma unroll
    for (int j = 0; j < 4; ++j)
      acc[i][j] = (f32x4){0.f, 0.f, 0.f, 0.f};

  const int arow = tid >> 2, au = tid & 3;
  const int aks = au ^ ((arow >> 1) & 3);
  const unsigned short* a_g = A + (size_t)(n0 + arow) * K + aks * 8;
  const int brow1 = (tid + 512) >> 2;
  const int bks0 = au ^ ((arow >> 1) & 3);
  const int bks1 = au ^ ((brow1 >> 1) & 3);
  const unsigned short* b_g0 = BT + (size_t)(m0 + arow) * K + bks0 * 8;
  const unsigned short* b_g1 = BT + (size_t)(m0 + brow1) * K + bks1 * 8;

  int a_off[4], b_off[4];
  #pragma unroll
  for (int f = 0; f < 4; ++f) {
    int row = wr * 64 + f * 16 + (lane & 15);
    a_off[f] = row * 64 + ((g ^ ((row >> 1) & 3)) << 4);
    int col = wc * 64 + f * 16 + (lane & 15);
    b_off[f] = col * 64 + ((g ^ ((col >> 1) & 3)) << 4);
  }

#define MM5_STAGE(buf, kk) do {                                  \
    GLOAD_LDS16(a_g + (kk), As[buf] + tid * 8);                  \
    GLOAD_LDS16(b_g0 + (kk), Bs[buf] + tid * 8);                 \
    GLOAD_LDS16(b_g1 + (kk), Bs[buf] + (tid + 512) * 8); } while (0)

#define MM5_COMPUTE(buf) do {                                    \
    bf16x8 af[4], bfr[4];                                        \
    _Pragma("unroll")                                            \
    for (int f = 0; f < 4; ++f) {                                \
      af[f]  = *(const bf16x8*)((const char*)As[buf] + a_off[f]);\
      bfr[f] = *(const bf16x8*)((const char*)Bs[buf] + b_off[f]);\
    }                                                            \
    _Pragma("unroll")                                            \
    for (int i = 0; i < 4; ++i)                                  \
      _Pragma("unroll")                                          \
      for (int j = 0; j < 4; ++j)                                \
        acc[i][j] = __builtin_amdgcn_mfma_f32_16x16x32_bf16(af[i], bfr[j], acc[i][j], 0, 0, 0); } while (0)

  MM5_STAGE(0, 0);
  MM5_STAGE(1, 32);
  int bc = 0, bp = 2;
  for (int k0 = 0; k0 < K; k0 += 32) {
    if (k0 + 32 < K) asm volatile("s_waitcnt vmcnt(3)" ::: "memory");
    else             asm volatile("s_waitcnt vmcnt(0)" ::: "memory");
    SCHED(); SBAR(); SCHED();
    if (k0 + 64 < K) MM5_STAGE(bp, k0 + 64);  // safe: readers finished before barrier
    MM5_COMPUTE(bc);
    bc = (bc == 2) ? 0 : bc + 1;
    bp = (bp == 2) ? 0 : bp + 1;
  }

  if (OMODE == 0) {
    #pragma unroll
    for (int fc = 0; fc < 4; ++fc) {
      int colg = m0 + wc * 64 + fc * 16 + (lane & 15);
      float bz = bias ? bias[colg] : 0.f;
      #pragma unroll
      for (int fr = 0; fr < 4; ++fr) {
        #pragma unroll
        for (int i = 0; i < 4; ++i) {
          int rowg = n0 + wr * 64 + fr * 16 + (g << 2) + i;
          float v = acc[fr][fc][i] + bz;
          if (res) v += res[(size_t)rowg * M + colg];
          if (relu) v = fmaxf(v, 0.f);
          if (Cf) Cf[(size_t)rowg * M + colg] = v;
          else    Ch[(size_t)rowg * M + colg] = f2b(v);
        }
      }
    }
  } else if (OMODE == 3) {
    unsigned short* kb  = Ch + (size_t)NT * Dn;
    unsigned short* vtb = Ch + 2 * (size_t)NT * Dn;
    #pragma unroll
    for (int fc = 0; fc < 4; ++fc) {
      int colg = m0 + wc * 64 + fc * 16 + (lane & 15);
      int sel = colg >> 10, hh = (colg >> 6) & 15, e = colg & 63;
      #pragma unroll
      for (int fr = 0; fr < 4; ++fr) {
        int rowg0 = n0 + wr * 64 + fr * 16 + (g << 2);
        int b = rowg0 >> 10, t0 = rowg0 & 1023;
        if (sel == 2) {
          ushort4 pk;
          pk.x = f2b(acc[fr][fc][0]); pk.y = f2b(acc[fr][fc][1]);
          pk.z = f2b(acc[fr][fc][2]); pk.w = f2b(acc[fr][fc][3]);
          *(ushort4*)&vtb[(((size_t)(b * 16 + hh) * 64) + e) * 1024 + t0] = pk;
        } else {
          unsigned short* dst = (sel == 0) ? Ch : kb;
          #pragma unroll
          for (int i = 0; i < 4; ++i)
            dst[(((size_t)(b * 16 + hh) * 1024) + t0 + i) * 64 + e] = f2b(acc[fr][fc][i]);
        }
      }
    }
  } else {
    // OMODE 4: LM head.
    #pragma unroll
    for (int fr = 0; fr < 4; ++fr) {
      #pragma unroll
      for (int i = 0; i < 4; ++i) {
        int rloc = wr * 64 + fr * 16 + (g << 2) + i;
        int rowg = n0 + rloc;
        float es = 0.f;
        #pragma unroll
        for (int fc = 0; fc < 4; ++fc) {
          int colg = m0 + wc * 64 + fc * 16 + (lane & 15);
          float v = acc[fr][fc][i] + bias[colg];
          __builtin_nontemporal_store(v, &Cf[(size_t)rowg * M + colg]);
          es += __expf(v);
        }
        es += __shfl_xor(es, 1); es += __shfl_xor(es, 2);
        es += __shfl_xor(es, 4); es += __shfl_xor(es, 8);
        if ((lane & 15) == 0) rsum2[rloc * 4 + wc] = es;
      }
    }
    __syncthreads();
    if (tid < 128)
      atomicAdd(&rowsum[n0 + tid],
                rsum2[tid * 4 + 0] + rsum2[tid * 4 + 1] +
                rsum2[tid * 4 + 2] + rsum2[tid * 4 + 3]);
  }
#undef MM5_STAGE
#undef MM5_COMPUTE
}

// ---------------- MFMA flash attention (paired q-tiles, 3-buf 1-bar) -------
// q,k: [B][H][T][64] bf16; vt: [B][H][64][T] bf16; out ob: [NT][D] bf16
// Block handles q-tiles {pr, 15-pr} sequentially: uniform 17 KV-steps/block.
// 3 KV buffers, 2-deep prefetch, single barrier per step (stage after bar,
// into the buffer whose readers finished last step -- same as the GEMMs).
__global__ __launch_bounds__(256) void fattn_kernel(
    const unsigned short* __restrict__ qg, const unsigned short* __restrict__ kg,
    const unsigned short* __restrict__ vtg, unsigned short* __restrict__ ob) {
  const int bid = blockIdx.x;                  // 512 blocks
  const int pr = bid & 7, bh = bid >> 3;
  const int b = bh >> 4, h = bh & 15;
  const int tid = threadIdx.x, lane = tid & 63, w = tid >> 6, g = lane >> 4;

  __shared__ __align__(16) unsigned short Ks[3][64 * 64];
  __shared__ __align__(16) unsigned short Vs[3][64 * 64];
  __shared__ __align__(16) unsigned short Pb[4][16 * 64];

  const unsigned short* kbase = kg + (size_t)bh * Tn * HDn;
  const unsigned short* vbase = vtg + (size_t)bh * HDn * Tn;
  const float scale = 0.03125f;                 // D^-0.5 (reference scales by n_embd)
  unsigned short* pb = &Pb[w][0];

#define FA_STAGE(buf, s0_) do {                                              \
    _Pragma("unroll")                                                        \
    for (int r = 0; r < 2; ++r) {                                            \
      int c = tid + 256 * r;                                                 \
      int srow = c >> 3, u = c & 7;                                          \
      GLOAD_LDS16(kbase + (size_t)((s0_) + srow) * HDn + ((u ^ (srow & 7)) * 8), Ks[buf] + c * 8); \
    }                                                                        \
    _Pragma("unroll")                                                        \
    for (int r = 0; r < 2; ++r) {                                            \
      int c = tid + 256 * r;                                                 \
      int d = c >> 3, u = c & 7;                                             \
      GLOAD_LDS16(vbase + (size_t)d * Tn + (s0_) + ((u ^ (d & 7)) * 8), Vs[buf] + c * 8); \
    } } while (0)

  #pragma unroll 1
  for (int half = 0; half < 2; ++half) {
    const int qt = half ? (15 - pr) : pr;
    const int qrow = qt * 64 + w * 16 + (lane & 15);
    const unsigned short* qptr = qg + ((size_t)bh * Tn + qrow) * HDn;
    bf16x8 qf0 = *(const bf16x8*)(qptr + g * 8);
    bf16x8 qf1 = *(const bf16x8*)(qptr + 32 + g * 8);

    f32x4 accO[4];
    #pragma unroll
    for (int dt = 0; dt < 4; ++dt) accO[dt] = (f32x4){0.f, 0.f, 0.f, 0.f};
    float mrun[4] = {-1e30f, -1e30f, -1e30f, -1e30f};
    float lrun[4] = {0.f, 0.f, 0.f, 0.f};
    const int qout0 = qt * 64 + w * 16 + 4 * g;
    const int nsteps = qt + 1;

    FA_STAGE(0, 0);
    if (nsteps > 1) FA_STAGE(1, 64);
    int bc = 0, bp = 2;

    for (int st = 0; st < nsteps; ++st) {
      const int s0 = st * 64;
      if (st + 1 < nsteps) asm volatile("s_waitcnt vmcnt(4)" ::: "memory");
      else                 asm volatile("s_waitcnt vmcnt(0)" ::: "memory");
      SCHED(); SBAR(); SCHED();
      if (st + 2 < nsteps) FA_STAGE(bp, s0 + 128);  // readers of bp done last step

      float p[4][4];
      #pragma unroll
      for (int sub = 0; sub < 4; ++sub) {
        int srow = sub * 16 + (lane & 15);
        const char* kr = (const char*)Ks[bc] + srow * 128;
        bf16x8 kf0 = *(const bf16x8*)(kr + ((g ^ (srow & 7)) * 16));
        bf16x8 kf1 = *(const bf16x8*)(kr + (((4 + g) ^ (srow & 7)) * 16));
        f32x4 s4 = (f32x4){0.f, 0.f, 0.f, 0.f};
        s4 = __builtin_amdgcn_mfma_f32_16x16x32_bf16(qf0, kf0, s4, 0, 0, 0);
        s4 = __builtin_amdgcn_mfma_f32_16x16x32_bf16(qf1, kf1, s4, 0, 0, 0);
        int sg = s0 + srow;
        #pragma unroll
        for (int i = 0; i < 4; ++i)
          p[sub][i] = (sg > qout0 + i) ? -1e30f : s4[i] * scale;
      }

      #pragma unroll
      for (int i = 0; i < 4; ++i) {
        float v = fmaxf(fmaxf(p[0][i], p[1][i]), fmaxf(p[2][i], p[3][i]));
        v = fmaxf(v, __shfl_xor(v, 1)); v = fmaxf(v, __shfl_xor(v, 2));
        v = fmaxf(v, __shfl_xor(v, 4)); v = fmaxf(v, __shfl_xor(v, 8));
        float nm = fmaxf(mrun[i], v);
        float fac = __expf(mrun[i] - nm);
        mrun[i] = nm;
        #pragma unroll
        for (int dt = 0; dt < 4; ++dt) accO[dt][i] *= fac;
        float sum = 0.f;
        #pragma unroll
        for (int sub = 0; sub < 4; ++sub) {
          float e = __expf(p[sub][i] - nm);
          p[sub][i] = e;
          sum += e;
        }
        sum += __shfl_xor(sum, 1); sum += __shfl_xor(sum, 2);
        sum += __shfl_xor(sum, 4); sum += __shfl_xor(sum, 8);
        lrun[i] = lrun[i] * fac + sum;
      }

      #pragma unroll
      for (int sub = 0; sub < 4; ++sub) {
        int s = sub * 16 + (lane & 15);
        #pragma unroll
        for (int i = 0; i < 4; ++i) {
          int q = 4 * g + i;
          pb[q * 64 + (((s >> 3) ^ (q & 7)) * 8) + (s & 7)] = f2b(p[sub][i]);
        }
      }

      #pragma unroll
      for (int sc = 0; sc < 2; ++sc) {
        int qq = lane & 15;
        bf16x8 pa = *(const bf16x8*)((const char*)pb + qq * 128 + (((sc * 4 + g) ^ (qq & 7)) * 16));
        #pragma unroll
        for (int dt = 0; dt < 4; ++dt) {
          int d = dt * 16 + (lane & 15);
          bf16x8 vf = *(const bf16x8*)((const char*)Vs[bc] + d * 128 + (((sc * 4 + g) ^ (d & 7)) * 16));
          accO[dt] = __builtin_amdgcn_mfma_f32_16x16x32_bf16(pa, vf, accO[dt], 0, 0, 0);
        }
      }

      bc = (bc == 2) ? 0 : bc + 1;
      bp = (bp == 2) ? 0 : bp + 1;
    }
    // drain any in-flight stages before next half restages buffers
    asm volatile("s_waitcnt vmcnt(0)" ::: "memory");
    SCHED(); SBAR(); SCHED();

    float rinv[4];
    #pragma unroll
    for (int i = 0; i < 4; ++i) rinv[i] = 1.0f / lrun[i];
    #pragma unroll
    for (int dt = 0; dt < 4; ++dt) {
      int dcol = h * 64 + dt * 16 + (lane & 15);
      #pragma unroll
      for (int i = 0; i < 4; ++i) {
        int t = qout0 + i;
        ob[((size_t)(b * Tn + t)) * Dn + dcol] = f2b(accO[dt][i] * rinv[i]);
      }
    }
  }
#undef FA_STAGE
}

// ---------------- final loss: nll from gathered target logit + rowsum ------
__global__ __launch_bounds__(256) void loss_kernel(
    const float* __restrict__ logits, const float* __restrict__ rowsum,
    const int* __restrict__ target, float* __restrict__ out_loss) {
  __shared__ float red[4];
  int lane = threadIdx.x & 63, w = threadIdx.x >> 6;
  float s = 0.f;
  for (int row = threadIdx.x; row < NT; row += 256) {
    float lt = logits[(size_t)row * Vn + target[row]];
    s += logf(rowsum[row]) - lt;          // -(lt - log(sum))
  }
  #pragma unroll
  for (int off = 32; off > 0; off >>= 1) s += __shfl_down(s, off, 64);
  if (lane == 0) red[w] = s;
  __syncthreads();
  if (threadIdx.x == 0)
    *out_loss = (red[0] + red[1] + red[2] + red[3]) * (1.0f / NT);
}

// ---------------------------------------------------------------------------
static inline void launch_wcast(const float* src, unsigned short* dst, int K, int M,
                                long long bsk, long long bsh, hipStream_t s) {
  dim3 g(M >> 6, K >> 6);
  wcast_kernel<<<g, 256, 0, s>>>(src, dst, K, M, bsk, bsh);
}

static inline void launch_mm(const unsigned short* A, const unsigned short* BT,
                             const float* bias, const float* res,
                             float* Cf, unsigned short* Ch,
                             int N, int K, int M, int relu, hipStream_t s) {
  dim3 g(N >> 7, M >> 7);          // n fast, m slow: B-panel temporal locality
  mm_bf16<<<g, 512, 0, s>>>(A, BT, bias, res, Cf, Ch, N, K, M, relu);
}

template<int OMODE>
static inline void launch_mm512(const unsigned short* A, const unsigned short* BT,
                                const float* bias, const float* res,
                                float* Cf, unsigned short* Ch, float* rowsum,
                                int N, int K, int M, int relu, hipStream_t s) {
  dim3 g(N >> 7, M >> 8);          // n fast, m slow
  mm512_bf16<OMODE><<<g, 512, 0, s>>>(A, BT, bias, res, Cf, Ch, rowsum, N, K, M, relu);
}

extern "C" void kernel_launch(void* const* d_in, const int* in_sizes, int n_in,
                              void* d_out, int out_size, void* d_ws, size_t ws_size,
                              hipStream_t stream) {
  const int*   idx    = (const int*)d_in[0];
  const int*   target = (const int*)d_in[1];
  const float* tok    = (const float*)d_in[2];
  const float* pos    = (const float*)d_in[3];
  const float* wq     = (const float*)d_in[4];
  const float* wk     = (const float*)d_in[5];
  const float* wv     = (const float*)d_in[6];
  const float* wproj  = (const float*)d_in[7];
  const float* bproj  = (const float*)d_in[8];
  const float* ln1g   = (const float*)d_in[9];
  const float* ln1b   = (const float*)d_in[10];
  const float* ln2g   = (const float*)d_in[11];
  const float* ln2b   = (const float*)d_in[12];
  const float* w1     = (const float*)d_in[13];
  const float* b1     = (const float*)d_in[14];
  const float* w2     = (const float*)d_in[15];
  const float* b2     = (const float*)d_in[16];
  const float* lnfg   = (const float*)d_in[17];
  const float* lnfb   = (const float*)d_in[18];
  const float* wlm    = (const float*)d_in[19];
  const float* blm    = (const float*)d_in[20];

  float* out = (float*)d_out;          // logits [4096,32000] + loss scalar

  char* p = (char*)d_ws;
  float* x  = (float*)p;                 p += (size_t)NT * Dn * 4;
  unsigned short* xn = (unsigned short*)p; p += (size_t)NT * Dn * 2;
  unsigned short* reg = (unsigned short*)p; p += (size_t)NT * 4 * Dn * 2;
  unsigned short* wT = (unsigned short*)p; p += (size_t)Vn * Dn * 2;
  float* rowsum = (float*)p;

  unsigned short* qb  = reg;                         // [B][H][T][64]
  unsigned short* kb  = reg + (size_t)NT * Dn;       // [B][H][T][64]
  unsigned short* vtb = reg + 2 * (size_t)NT * Dn;   // [B][H][64][T]
  unsigned short* ob  = reg + 3 * (size_t)NT * Dn;   // [NT][D]
  unsigned short* hb  = reg;                         // MLP hidden, disjoint in time

  embed_kernel<<<NT, 256, 0, stream>>>(idx, tok, pos, x);

  for (int l = 0; l < Ln; ++l) {
    const float* wq_l = wq + (size_t)l * Hn * Dn * HDn;
    const float* wk_l = wk + (size_t)l * Hn * Dn * HDn;
    const float* wv_l = wv + (size_t)l * Hn * Dn * HDn;

    ln_kernel<<<NT, 256, 0, stream>>>(x, ln1g + l * Dn, ln1b + l * Dn, xn);

    // fused QKV: wT rows [0,1024)=q, [1024,2048)=k, [2048,3072)=v, one launch
    {
      dim3 g3(16, 16, 3);
      wcast3_kernel<<<g3, 256, 0, stream>>>(wq_l, wk_l, wv_l, wT);
    }
    launch_mm512<3>(xn, wT, nullptr, nullptr, nullptr, qb, nullptr, NT, Dn, 3072, 0, stream);

    fattn_kernel<<<Bn * Hn * 8, 256, 0, stream>>>(qb, kb, vtb, ob);

    launch_wcast(wproj + (size_t)l * Dn * Dn, wT, Dn, Dn, Dn, 64, stream);
    launch_mm(ob, wT, bproj + l * Dn, x, x, nullptr, NT, Dn, Dn, 0, stream);

    ln_kernel<<<NT, 256, 0, stream>>>(x, ln2g + l * Dn, ln2b + l * Dn, xn);

    launch_wcast(w1 + (size_t)l * Dn * 4 * Dn, wT, Dn, 4 * Dn, 4 * Dn, 64, stream);
    launch_mm512<0>(xn, wT, b1 + l * 4 * Dn, nullptr, nullptr, hb, nullptr, NT, Dn, 4 * Dn, 1, stream);
    launch_wcast(w2 + (size_t)l * 4 * Dn * Dn, wT, 4 * Dn, Dn, Dn, 64, stream);
    launch_mm(hb, wT, b2 + l * Dn, x, x, nullptr, NT, 4 * Dn, Dn, 0, stream);
  }

  ln_kernel<<<NT, 256, 0, stream>>>(x, lnfg, lnfb, xn);

  // logits + fused per-row exp-sums
  hipMemsetAsync(rowsum, 0, NT * sizeof(float), stream);
  launch_wcast(wlm, wT, Dn, Vn, Vn, 64, stream);
  launch_mm512<4>(xn, wT, blm, nullptr, out, nullptr, rowsum, NT, Dn, Vn, 0, stream);

  loss_kernel<<<1, 256, 0, stream>>>(out, rowsum, target, out + (size_t)NT * Vn);
}